// Round 11
// baseline (195.911 us; speedup 1.0000x reference)
//
#include <hip/hip_runtime.h>

#define H_ 448
#define CIN_ 128
#define HW_ (448*96)   // 43008
#define PPB 48

__device__ __forceinline__ float lrelu(float v){ return v > 0.0f ? v : 0.01f*v; }

// XCD-pairing block decode: the two half-line blocks of line h land on the same XCD.
__device__ __forceinline__ void decode_block(int d, int& h, int& wb){
    const int r = d & 15, q = d >> 4;
    h  = (r & 7) + (q << 3);
    wb = (r >> 3) * PPB;
}

// Counting sort of PPB pixels by class (NC classes). All threads must call.
template<int NC>
__device__ __forceinline__ void sort_by_class(const unsigned char* s_cls, short* s_perm,
                                              int* s_cnt, int* s_off, int t)
{
    if (t < NC){
        int c = 0;
        for (int p = 0; p < PPB; p++) if (s_cls[p] == (unsigned char)t) c++;
        s_cnt[t] = c;
    }
    __syncthreads();
    if (t == 0){
        int a = 0;
        for (int c = 0; c < NC; c++){ s_off[c] = a; a += s_cnt[c]; }
    }
    __syncthreads();
    if (t < NC){
        int o = s_off[t];
        for (int p = 0; p < PPB; p++) if (s_cls[p] == (unsigned char)t) s_perm[o++] = (short)p;
    }
    __syncthreads();
}

// Build 2-pixel single-class chunks from sorted runs (pad odd tails).
template<int NC>
__device__ __forceinline__ void build_pairs(const int* s_cnt, const int* s_off,
                                            int* s_chunk, int* s_nch, int t)
{
    if (t == 0){
        int n = 0;
        for (int c = 0; c < NC; c++){
            const int cnt = s_cnt[c];
            for (int b = 0; b < cnt; b += 2) s_chunk[n++] = (c << 16) | (s_off[c] + b);
        }
        *s_nch = n;
    }
    __syncthreads();
}

// ================= K1: stage 1 (half-line blocks) — unchanged from R10 =================
__global__ __launch_bounds__(384, 4)
void k1_stage1(const float* __restrict__ X,
               const float* __restrict__ w1_0, const float* __restrict__ b1_0,
               const float* __restrict__ w1_1, const float* __restrict__ b1_1,
               const float* __restrict__ w1_2, const float* __restrict__ b1_2,
               unsigned char* __restrict__ inds1)
{
    __shared__ float s_w0[4096];
    __shared__ float s_w1[1024];
    __shared__ float s_w2[256];
    __shared__ float s_A[PPB*33];
    __shared__ float s_B[PPB*33];

    int h, wb; decode_block(blockIdx.x, h, wb);
    const int t  = threadIdx.x;
    const int w  = t % PPB;
    const int s  = t / PPB;          // 0..7 owns 4 channels
    const int hw = h*96 + wb + w;

    const float* g0 = w1_0 + (size_t)h*4096;
    for (int j = t; j < 4096; j += 384) s_w0[j] = g0[j];
    const float* g1 = w1_1 + (size_t)h*1024;
    for (int j = t; j < 1024; j += 384) s_w1[j] = g1[j];
    const float* g2 = w1_2 + (size_t)h*256;
    for (int j = t; j < 256; j += 384) s_w2[j] = g2[j];
    __syncthreads();

    // L0: 128 -> 32
    {
        float acc[4];
        const float* bp = b1_0 + h*32 + s*4;
        #pragma unroll
        for (int k=0;k<4;k++) acc[k] = bp[k];
        #pragma unroll 4
        for (int i4=0;i4<32;i4++){
            const float x0 = X[(size_t)(4*i4+0)*HW_ + hw];
            const float x1 = X[(size_t)(4*i4+1)*HW_ + hw];
            const float x2 = X[(size_t)(4*i4+2)*HW_ + hw];
            const float x3 = X[(size_t)(4*i4+3)*HW_ + hw];
            #pragma unroll
            for (int k=0;k<4;k++){
                const float4 q = *(const float4*)&s_w0[(s*4+k)*128 + 4*i4];
                acc[k] += x0*q.x; acc[k] += x1*q.y; acc[k] += x2*q.z; acc[k] += x3*q.w;
            }
        }
        #pragma unroll
        for (int k=0;k<4;k++) s_A[w*33 + s*4 + k] = lrelu(acc[k]);
    }
    __syncthreads();

    // L1: 32 -> 32
    {
        float acc[4];
        const float* bp = b1_1 + h*32 + s*4;
        #pragma unroll
        for (int k=0;k<4;k++) acc[k] = bp[k];
        #pragma unroll
        for (int i4=0;i4<8;i4++){
            const float x0 = s_A[w*33 + 4*i4+0];
            const float x1 = s_A[w*33 + 4*i4+1];
            const float x2 = s_A[w*33 + 4*i4+2];
            const float x3 = s_A[w*33 + 4*i4+3];
            #pragma unroll
            for (int k=0;k<4;k++){
                const float4 q = *(const float4*)&s_w1[(s*4+k)*32 + 4*i4];
                acc[k] += x0*q.x; acc[k] += x1*q.y; acc[k] += x2*q.z; acc[k] += x3*q.w;
            }
        }
        #pragma unroll
        for (int k=0;k<4;k++) s_B[w*33 + s*4 + k] = lrelu(acc[k]);
    }
    __syncthreads();

    // L2: 32 -> 8 (each s owns 1 output)
    {
        float acc = b1_2[h*8 + s];
        #pragma unroll
        for (int i4=0;i4<8;i4++){
            const float4 q = *(const float4*)&s_w2[s*32 + 4*i4];
            acc += s_B[w*33 + 4*i4+0]*q.x;
            acc += s_B[w*33 + 4*i4+1]*q.y;
            acc += s_B[w*33 + 4*i4+2]*q.z;
            acc += s_B[w*33 + 4*i4+3]*q.w;
        }
        s_A[w*33 + s] = acc;
    }
    __syncthreads();

    if (s == 0){
        const float* sc = &s_A[w*33];
        float best = sc[0]; int bi = 0;
        #pragma unroll
        for (int k=1;k<8;k++){ const float v = sc[k]; if (v > best){ best = v; bi = k; } }
        inds1[hw] = (unsigned char)bi;
    }
}

// ================= K2/K3: sorted pair-sharing demand-gather =================
// 8-lane group computes TWO same-expert pixels: each float4 weight load serves both.
template<int NC, bool S3>
__global__ __launch_bounds__(384, 4)
void condmul_pair(const float* __restrict__ X,
                  const float* __restrict__ w0, const float* __restrict__ b0,
                  const float* __restrict__ w1, const float* __restrict__ b1,
                  const float* __restrict__ w2, const float* __restrict__ b2,
                  const unsigned char* __restrict__ route,
                  signed char* __restrict__ raw12,
                  unsigned char* __restrict__ cls2,
                  int* __restrict__ out)
{
    __shared__ float s_A[PPB*36];
    __shared__ float s_B[PPB*36];
    __shared__ unsigned char s_cls[PPB];
    __shared__ short s_perm[PPB];
    __shared__ int   s_cnt[NC];
    __shared__ int   s_off[NC];
    __shared__ int   s_chunk[PPB];
    __shared__ int   s_nch;

    int h, wb; decode_block(blockIdx.x, h, wb);
    const int t = threadIdx.x;
    if (t < PPB) s_cls[t] = route[h*96 + wb + t];
    __syncthreads();
    sort_by_class<NC>(s_cls, s_perm, s_cnt, s_off, t);
    build_pairs<NC>(s_cnt, s_off, s_chunk, &s_nch, t);

    const int g = t >> 3;   // group 0..47: owns chunk g
    const int j = t & 7;    // lane: owns channels 4j..4j+3 (L0/L1), {2j,2j+1} (L2)
    if (g >= s_nch) return;

    const int info = s_chunk[g];
    const int c    = info >> 16;
    const int base = info & 0xffff;
    const bool has2 = (base + 1) < (s_off[c] + s_cnt[c]);
    const int sp0 = s_perm[base];
    const int sp1 = has2 ? s_perm[base + 1] : sp0;
    const long e = (long)h*NC + c;
    const int hw0 = h*96 + wb + sp0;
    const int hw1 = h*96 + wb + sp1;
    const float* W0 = w0 + e*4096 + j*4;
    const float* W1 = w1 + e*1024 + j*4;
    const float* W2 = w2 + e*512  + j*2;

    // L0: 128 -> 32 — one float4 weight load per row serves both pixels
    float4 a0, a1;
    a0 = a1 = *(const float4*)&b0[e*32 + j*4];
    #pragma unroll 8
    for (int i=0;i<128;i++){
        const float4 q = *(const float4*)&W0[i*32];
        const float x0 = X[(size_t)i*HW_ + hw0];
        const float x1 = X[(size_t)i*HW_ + hw1];
        a0.x += x0*q.x; a0.y += x0*q.y; a0.z += x0*q.z; a0.w += x0*q.w;
        a1.x += x1*q.x; a1.y += x1*q.y; a1.z += x1*q.z; a1.w += x1*q.w;
    }
    *(float4*)&s_A[sp0*36 + j*4] = make_float4(lrelu(a0.x),lrelu(a0.y),lrelu(a0.z),lrelu(a0.w));
    if (has2)
        *(float4*)&s_A[sp1*36 + j*4] = make_float4(lrelu(a1.x),lrelu(a1.y),lrelu(a1.z),lrelu(a1.w));

    // L1: 32 -> 32 (acts group-local in LDS; same wave -> no barrier)
    float4 c0, c1;
    c0 = c1 = *(const float4*)&b1[e*32 + j*4];
    #pragma unroll 8
    for (int i=0;i<32;i++){
        const float4 q = *(const float4*)&W1[i*32];
        const float x0 = s_A[sp0*36 + i];
        const float x1 = s_A[sp1*36 + i];
        c0.x += x0*q.x; c0.y += x0*q.y; c0.z += x0*q.z; c0.w += x0*q.w;
        c1.x += x1*q.x; c1.y += x1*q.y; c1.z += x1*q.z; c1.w += x1*q.w;
    }
    *(float4*)&s_B[sp0*36 + j*4] = make_float4(lrelu(c0.x),lrelu(c0.y),lrelu(c0.z),lrelu(c0.w));
    if (has2)
        *(float4*)&s_B[sp1*36 + j*4] = make_float4(lrelu(c1.x),lrelu(c1.y),lrelu(c1.z),lrelu(c1.w));

    // L2: 32 -> 16 (lane owns channels 2j, 2j+1)
    float2 d0, d1;
    d0 = d1 = *(const float2*)&b2[e*16 + j*2];
    #pragma unroll 8
    for (int i=0;i<32;i++){
        const float2 r = *(const float2*)&W2[i*16];
        const float x0 = s_B[sp0*36 + i];
        const float x1 = s_B[sp1*36 + i];
        d0.x += x0*r.x; d0.y += x0*r.y;
        d1.x += x1*r.x; d1.y += x1*r.y;
    }

    // per-pixel argmax over 16 channels via 8-lane butterfly (first-occurrence ties)
    {
        float best = d0.x; int bi = j*2;
        if (d0.y > best){ best = d0.y; bi = j*2+1; }
        #pragma unroll
        for (int off=1; off<8; off<<=1){
            const float ob = __shfl_xor(best, off, 64);
            const int  obi = __shfl_xor(bi,  off, 64);
            if (ob > best || (ob == best && obi < bi)){ best = ob; bi = obi; }
        }
        if (j == 0){
            if (S3){
                int v = (int)raw12[hw0]*8 + bi - 4;
                v = v < 0 ? 0 : (v > 511 ? 511 : v);
                out[hw0] = v;
            } else {
                const int raw = c*8 + bi - 4;
                raw12[hw0] = (signed char)raw;
                cls2[hw0]  = (unsigned char)(raw < 0 ? 0 : (raw > 63 ? 63 : raw));
            }
        }
    }
    if (has2){
        float best = d1.x; int bi = j*2;
        if (d1.y > best){ best = d1.y; bi = j*2+1; }
        #pragma unroll
        for (int off=1; off<8; off<<=1){
            const float ob = __shfl_xor(best, off, 64);
            const int  obi = __shfl_xor(bi,  off, 64);
            if (ob > best || (ob == best && obi < bi)){ best = ob; bi = obi; }
        }
        if (j == 0){
            if (S3){
                int v = (int)raw12[hw1]*8 + bi - 4;
                v = v < 0 ? 0 : (v > 511 ? 511 : v);
                out[hw1] = v;
            } else {
                const int raw = c*8 + bi - 4;
                raw12[hw1] = (signed char)raw;
                cls2[hw1]  = (unsigned char)(raw < 0 ? 0 : (raw > 63 ? 63 : raw));
            }
        }
    }
}

extern "C" void kernel_launch(void* const* d_in, const int* in_sizes, int n_in,
                              void* d_out, int out_size, void* d_ws, size_t ws_size,
                              hipStream_t stream) {
    const float* X    = (const float*)d_in[0];
    const float* w1_0 = (const float*)d_in[1];
    const float* b1_0 = (const float*)d_in[2];
    const float* w1_1 = (const float*)d_in[3];
    const float* b1_1 = (const float*)d_in[4];
    const float* w1_2 = (const float*)d_in[5];
    const float* b1_2 = (const float*)d_in[6];
    const float* w2_0 = (const float*)d_in[7];
    const float* b2_0 = (const float*)d_in[8];
    const float* w2_1 = (const float*)d_in[9];
    const float* b2_1 = (const float*)d_in[10];
    const float* w2_2 = (const float*)d_in[11];
    const float* b2_2 = (const float*)d_in[12];
    const float* w3_0 = (const float*)d_in[13];
    const float* b3_0 = (const float*)d_in[14];
    const float* w3_1 = (const float*)d_in[15];
    const float* b3_1 = (const float*)d_in[16];
    const float* w3_2 = (const float*)d_in[17];
    const float* b3_2 = (const float*)d_in[18];
    int* out = (int*)d_out;

    unsigned char* inds1 = (unsigned char*)d_ws;
    unsigned char* cls2  = inds1 + HW_;
    signed char*   raw12 = (signed char*)(cls2 + HW_);

    k1_stage1<<<H_*2, 384, 0, stream>>>(X, w1_0, b1_0, w1_1, b1_1, w1_2, b1_2, inds1);
    condmul_pair<8,  false><<<H_*2, 384, 0, stream>>>(X, w2_0, b2_0, w2_1, b2_1, w2_2, b2_2,
                                                      inds1, raw12, cls2, out);
    condmul_pair<64, true ><<<H_*2, 384, 0, stream>>>(X, w3_0, b3_0, w3_1, b3_1, w3_2, b3_2,
                                                      cls2, raw12, cls2, out);
}